// Round 4
// baseline (48.452 us; speedup 1.0000x reference)
//
#include <hip/hip_runtime.h>
#include <hip/hip_bf16.h>

// DomainBatchNorm: out[b,f] = x[b,f] * scale[d(b),f] + shift[d(b),f]
//   k1 (tiny): fold scale = gamma*rsqrt(var+eps), shift = beta - mean*scale
//              into d_ws (64 KB, L2-resident).
//   k2: PERSISTENT grid-stride apply — 2048 blocks x 4 waves; each wave
//       streams 4 rows with a hand-written software pipeline (prefetch next
//       row's x+mask during current row's param-load/FMA/store). Mirrors the
//       structure of the 6.3-7 TB/s copy/fill benches instead of 8192
//       short-lived blocks.

#define F_DIM 1024
#define D_DIM 8
#define EPSV  1e-5f

typedef float f4 __attribute__((ext_vector_type(4)));

__global__ __launch_bounds__(256) void dbn_fold(
    const f4* __restrict__ gammas, const f4* __restrict__ betas,
    const f4* __restrict__ means,  const f4* __restrict__ vars,
    f4* __restrict__ scale, f4* __restrict__ shift)
{
    const int i = blockIdx.x * 256 + threadIdx.x;   // 0 .. 2047
    if (i >= D_DIM * (F_DIM / 4)) return;
    f4 g = gammas[i], b = betas[i], m = means[i], v = vars[i];
    f4 s, h;
    s.x = g.x * rsqrtf(v.x + EPSV); h.x = fmaf(-m.x, s.x, b.x);
    s.y = g.y * rsqrtf(v.y + EPSV); h.y = fmaf(-m.y, s.y, b.y);
    s.z = g.z * rsqrtf(v.z + EPSV); h.z = fmaf(-m.z, s.z, b.z);
    s.w = g.w * rsqrtf(v.w + EPSV); h.w = fmaf(-m.w, s.w, b.w);
    scale[i] = s; shift[i] = h;
}

// Persistent wave-per-row, software-pipelined. Lane l covers float4 columns
// l, l+64, l+128, l+192 (16B/lane, coalesced). All branches wave-uniform.
__global__ __launch_bounds__(256, 4) void dbn_apply_persist(
    const f4* __restrict__ x, const float* __restrict__ mask,
    const f4* __restrict__ scale, const f4* __restrict__ shift,
    f4* __restrict__ out, int B, int wave_stride)
{
    const int wave = threadIdx.x >> 6;
    const int lane = threadIdx.x & 63;
    const int w    = (blockIdx.x << 2) | wave;      // global wave id
    const int c0 = lane, c1 = lane + 64, c2 = lane + 128, c3 = lane + 192;

    int row = w;
    if (row >= B) return;

    // Prologue: current row's mask + x in flight.
    float mv = (lane < D_DIM) ? mask[(size_t)row * D_DIM + lane] : 0.0f;
    const f4* xr = x + (size_t)row * (F_DIM / 4);
    f4 x0 = xr[c0], x1 = xr[c1], x2 = xr[c2], x3 = xr[c3];

    while (true) {
        const int nrow = row + wave_stride;
        const bool more = (nrow < B);

        // Prefetch next row (independent of current compute).
        float nmv = 0.0f;
        f4 nx0, nx1, nx2, nx3;
        if (more) {
            nmv = (lane < D_DIM) ? mask[(size_t)nrow * D_DIM + lane] : 0.0f;
            const f4* nxr = x + (size_t)nrow * (F_DIM / 4);
            nx0 = nxr[c0]; nx1 = nxr[c1]; nx2 = nxr[c2]; nx3 = nxr[c3];
        }

        // Resolve current row's domain (one-hot -> ballot -> ffs).
        unsigned long long bal = __ballot(mv > 0.5f);
        const int d = __ffsll(bal) - 1;
        const f4* __restrict__ sc = scale + (size_t)d * (F_DIM / 4);
        const f4* __restrict__ sh = shift + (size_t)d * (F_DIM / 4);
        f4 s0 = sc[c0], s1 = sc[c1], s2 = sc[c2], s3 = sc[c3];
        f4 h0 = sh[c0], h1 = sh[c1], h2 = sh[c2], h3 = sh[c3];

        f4* __restrict__ orow = out + (size_t)row * (F_DIM / 4);
        f4 o0, o1, o2, o3;
        o0.x = fmaf(x0.x, s0.x, h0.x); o0.y = fmaf(x0.y, s0.y, h0.y);
        o0.z = fmaf(x0.z, s0.z, h0.z); o0.w = fmaf(x0.w, s0.w, h0.w);
        o1.x = fmaf(x1.x, s1.x, h1.x); o1.y = fmaf(x1.y, s1.y, h1.y);
        o1.z = fmaf(x1.z, s1.z, h1.z); o1.w = fmaf(x1.w, s1.w, h1.w);
        o2.x = fmaf(x2.x, s2.x, h2.x); o2.y = fmaf(x2.y, s2.y, h2.y);
        o2.z = fmaf(x2.z, s2.z, h2.z); o2.w = fmaf(x2.w, s2.w, h2.w);
        o3.x = fmaf(x3.x, s3.x, h3.x); o3.y = fmaf(x3.y, s3.y, h3.y);
        o3.z = fmaf(x3.z, s3.z, h3.z); o3.w = fmaf(x3.w, s3.w, h3.w);

        __builtin_nontemporal_store(o0, &orow[c0]);
        __builtin_nontemporal_store(o1, &orow[c1]);
        __builtin_nontemporal_store(o2, &orow[c2]);
        __builtin_nontemporal_store(o3, &orow[c3]);

        if (!more) break;
        row = nrow; mv = nmv;
        x0 = nx0; x1 = nx1; x2 = nx2; x3 = nx3;
    }
}

// Fallback if ws too small: original wave-per-row, inline fold.
__global__ __launch_bounds__(256) void dbn_apply_inline(
    const f4* __restrict__ x, const float* __restrict__ mask,
    const f4* __restrict__ gammas, const f4* __restrict__ betas,
    const f4* __restrict__ means,  const f4* __restrict__ vars,
    f4* __restrict__ out, int B)
{
    const int wave = threadIdx.x >> 6;
    const int lane = threadIdx.x & 63;
    const int row  = (blockIdx.x << 2) | wave;
    if (row >= B) return;

    const f4* __restrict__ xr = x + (size_t)row * (F_DIM / 4);
    const int c0 = lane, c1 = lane + 64, c2 = lane + 128, c3 = lane + 192;
    f4 x0 = xr[c0], x1 = xr[c1], x2 = xr[c2], x3 = xr[c3];

    float mv = (lane < D_DIM) ? mask[(size_t)row * D_DIM + lane] : 0.0f;
    unsigned long long bal = __ballot(mv > 0.5f);
    const int d = __ffsll(bal) - 1;
    const size_t pb = (size_t)d * (F_DIM / 4);

    f4* __restrict__ orow = out + (size_t)row * (F_DIM / 4);

    #pragma unroll
    for (int k = 0; k < 4; ++k) {
        const int c = lane + (k << 6);
        f4 g = gammas[pb + c], b = betas[pb + c], m = means[pb + c], v = vars[pb + c];
        f4 xv = (k == 0) ? x0 : (k == 1) ? x1 : (k == 2) ? x2 : x3;
        f4 o; float s;
        s = g.x * rsqrtf(v.x + EPSV); o.x = fmaf(xv.x, s, fmaf(-m.x, s, b.x));
        s = g.y * rsqrtf(v.y + EPSV); o.y = fmaf(xv.y, s, fmaf(-m.y, s, b.y));
        s = g.z * rsqrtf(v.z + EPSV); o.z = fmaf(xv.z, s, fmaf(-m.z, s, b.z));
        s = g.w * rsqrtf(v.w + EPSV); o.w = fmaf(xv.w, s, fmaf(-m.w, s, b.w));
        __builtin_nontemporal_store(o, &orow[c]);
    }
}

extern "C" void kernel_launch(void* const* d_in, const int* in_sizes, int n_in,
                              void* d_out, int out_size, void* d_ws, size_t ws_size,
                              hipStream_t stream) {
    const float* x    = (const float*)d_in[0];
    const float* mask = (const float*)d_in[1];
    const float* gam  = (const float*)d_in[2];
    const float* bet  = (const float*)d_in[3];
    const float* mu   = (const float*)d_in[4];
    const float* var  = (const float*)d_in[5];
    float* out        = (float*)d_out;

    const int B = in_sizes[0] / F_DIM;             // 32768

    const size_t fold_bytes = (size_t)2 * D_DIM * F_DIM * sizeof(float); // 64 KB

    if (ws_size >= fold_bytes) {
        f4* scale = (f4*)d_ws;
        f4* shift = (f4*)((char*)d_ws + fold_bytes / 2);
        const int n_fold = D_DIM * (F_DIM / 4);    // 2048
        dbn_fold<<<(n_fold + 255) / 256, 256, 0, stream>>>(
            (const f4*)gam, (const f4*)bet, (const f4*)mu, (const f4*)var,
            scale, shift);

        // Persistent: 2048 blocks x 4 waves = 8192 waves; each streams
        // B/8192 = 4 rows, software-pipelined.
        int grid = 2048;
        int waves = grid * 4;
        if (waves > B) { grid = (B + 3) / 4; waves = grid * 4; }
        dbn_apply_persist<<<grid, 256, 0, stream>>>(
            (const f4*)x, mask, scale, shift, (f4*)out, B, waves);
    } else {
        const int grid = (B + 3) / 4;
        dbn_apply_inline<<<grid, 256, 0, stream>>>(
            (const f4*)x, mask, (const f4*)gam, (const f4*)bet,
            (const f4*)mu, (const f4*)var, (f4*)out, B);
    }
}